// Round 15
// baseline (389.431 us; speedup 1.0000x reference)
//
#include <hip/hip_runtime.h>
#include <hip/hip_bf16.h>
#include <hip/hip_fp16.h>

#define N_NODES 100000
#define N_EDGES 3200000
#define N_GRAPHS 256
#define D_IN 320
#define D_H 64

#define NBIN 391                    // ceil(N_NODES / 256) bins of 256 dst nodes
#define BIN_CAP 14336               // padded bin ~12154, sigma~172 -> +12 sigma
#define HIST_BLOCKS 256
#define HIST_CHUNK ((N_EDGES + HIST_BLOCKS - 1) / HIST_BLOCKS)
#define PART_BLOCKS 200
#define PART_CHUNK ((N_EDGES + PART_BLOCKS - 1) / PART_BLOCKS)   // 16000
#define COLB_CAP 5500000            // padded edges ~4.75M

// ---------------- CSR build (block-private chunk partition) ----------------

__global__ __launch_bounds__(256) void k_hist(const int* __restrict__ dst,
                                              int* __restrict__ ghist) {
    __shared__ int lh[NBIN];
    for (int i = threadIdx.x; i < NBIN; i += 256) lh[i] = 0;
    __syncthreads();
    int beg = blockIdx.x * HIST_CHUNK;
    int end = min(beg + HIST_CHUNK, N_EDGES);
    for (int e = beg + threadIdx.x; e < end; e += 256)
        atomicAdd(&lh[dst[e] >> 8], 1);
    __syncthreads();
    for (int i = threadIdx.x; i < NBIN; i += 256)
        if (lh[i]) atomicAdd(&ghist[i], lh[i]);
}

// scan real bin counts -> compact binbase (for ebuf) + gcur
__global__ __launch_bounds__(512) void k_scanbins(const int* __restrict__ ghist,
                                                  int* __restrict__ binbase,
                                                  int* __restrict__ gcur) {
    __shared__ int sa[512], sb[512];
    int t = threadIdx.x;
    int v = (t < NBIN) ? ghist[t] : 0;
    sa[t] = v;
    __syncthreads();
    int* in = sa; int* out = sb;
    for (int off = 1; off < 512; off <<= 1) {
        out[t] = in[t] + (t >= off ? in[t - off] : 0);
        __syncthreads();
        int* tmp = in; in = out; out = tmp;
    }
    int excl = in[t] - v;
    if (t < NBIN) { binbase[t] = excl; gcur[t] = excl; }
    if (t == 511) binbase[NBIN] = in[511];
}

// partition edges into 391 bins; block-private contiguous chunks per bin.
__global__ __launch_bounds__(256) void k_part(const int* __restrict__ src,
                                              const int* __restrict__ dst,
                                              int* __restrict__ gcur,
                                              int* __restrict__ ebuf) {
    __shared__ int lh[NBIN], gb[NBIN], cur[NBIN];
    for (int i = threadIdx.x; i < NBIN; i += 256) { lh[i] = 0; cur[i] = 0; }
    __syncthreads();
    int beg = blockIdx.x * PART_CHUNK;
    int end = min(beg + PART_CHUNK, N_EDGES);
    for (int e = beg + threadIdx.x; e < end; e += 256)
        atomicAdd(&lh[dst[e] >> 8], 1);
    __syncthreads();
    for (int i = threadIdx.x; i < NBIN; i += 256)
        gb[i] = lh[i] ? atomicAdd(&gcur[i], lh[i]) : 0;
    __syncthreads();
    for (int e = beg + threadIdx.x; e < end; e += 256) {
        int d = dst[e], s = src[e];
        int bin = d >> 8;
        int r = atomicAdd(&cur[bin], 1);
        ebuf[gb[bin] + r] = ((d & 255) << 17) | s;   // dst-low-8 | src(17b)
    }
}

// per bin: per-node degree -> padded degree (mult of 32), local padded
// offsets (lofs), dinv, padded bin total.
__global__ __launch_bounds__(256) void k_binpad(const int* __restrict__ binbase,
                                                const int* __restrict__ ebuf,
                                                int* __restrict__ pbin,
                                                int* __restrict__ lofs,
                                                float* __restrict__ dinv) {
    __shared__ int hc[256], sa[256], sb[256];
    int b = blockIdx.x, t = threadIdx.x;
    int e0 = binbase[b], e1 = binbase[b + 1];
    hc[t] = 0;
    __syncthreads();
    for (int i = e0 + t; i < e1; i += 256)
        atomicAdd(&hc[ebuf[i] >> 17], 1);
    __syncthreads();
    int deg = hc[t];
    int pdeg = (deg + 31) & ~31;
    sa[t] = pdeg;
    __syncthreads();
    int* in = sa; int* out = sb;
    for (int o = 1; o < 256; o <<= 1) {
        out[t] = in[t] + (t >= o ? in[t - o] : 0);
        __syncthreads();
        int* tm = in; in = out; out = tm;
    }
    int excl = in[t] - pdeg;
    lofs[(b << 8) + t] = excl;
    int node = (b << 8) + t;
    if (node < N_NODES) dinv[node] = rsqrtf((float)(deg + 1));  // +1 self loop
    if (t == 255) pbin[b] = in[255];
}

// scan padded bin totals -> pbinbase; also prowptr[N] and u's zero pad row.
__global__ __launch_bounds__(512) void k_scanp(const int* __restrict__ pbin,
                                               int* __restrict__ pbinbase,
                                               int* __restrict__ prowptr,
                                               __half* __restrict__ u) {
    __shared__ int sa[512], sb[512];
    int t = threadIdx.x;
    int v = (t < NBIN) ? pbin[t] : 0;
    sa[t] = v;
    __syncthreads();
    int* in = sa; int* out = sb;
    for (int off = 1; off < 512; off <<= 1) {
        out[t] = in[t] + (t >= off ? in[t - off] : 0);
        __syncthreads();
        int* tmp = in; in = out; out = tmp;
    }
    int excl = in[t] - v;
    if (t < NBIN) pbinbase[t] = excl;
    if (t == 511) { pbinbase[NBIN] = in[511]; prowptr[N_NODES] = in[511]; }
    if (t < 32) ((unsigned*)(u + (size_t)N_NODES * D_H))[t] = 0u;  // zero row
}

// per bin: place edges at padded local offsets, fill pads with sentinel,
// write col coalesced; emit prowptr.
__global__ __launch_bounds__(256) void k_sortbin(const int* __restrict__ binbase,
                                                 const int* __restrict__ pbinbase,
                                                 const int* __restrict__ lofs,
                                                 const int* __restrict__ ebuf,
                                                 int* __restrict__ col,
                                                 int* __restrict__ prowptr) {
    __shared__ int hc[256], sc[256];
    __shared__ int scol[BIN_CAP];
    int b = blockIdx.x, t = threadIdx.x;
    int d0 = b << 8;
    int e0 = binbase[b], e1 = binbase[b + 1];
    int pb0 = pbinbase[b], pb1 = pbinbase[b + 1];
    hc[t] = 0;
    __syncthreads();
    for (int i = e0 + t; i < e1; i += 256)
        atomicAdd(&hc[ebuf[i] >> 17], 1);
    __syncthreads();
    int lb = lofs[d0 + t];
    int deg = hc[t];
    int pdeg = (deg + 31) & ~31;
    sc[t] = lb;
    int node = d0 + t;
    if (node < N_NODES) prowptr[node] = pb0 + lb;
    __syncthreads();
    for (int i = e0 + t; i < e1; i += 256) {
        int pk = ebuf[i];
        int p = atomicAdd(&sc[pk >> 17], 1);
        if (p < BIN_CAP) scol[p] = pk & 0x1FFFF;
    }
    __syncthreads();
    for (int j = lb + deg; j < lb + pdeg; ++j)
        if (j < BIN_CAP) scol[j] = N_NODES;          // sentinel -> zero row
    __syncthreads();
    int n = pb1 - pb0;
    for (int i = t; i < n; i += 256) col[pb0 + i] = scol[i];
}

// ---------------- tiled GEMM transforms ----------------
// u[node][f] = half( (A[node,:] @ W)[f] * dinv[node] )
// K-chunk 32 (16.4 KB LDS -> 8 blocks/CU), swizzled transpose store.

// fp32 A (layer 1, K = 320)
template<int K>
__global__ __launch_bounds__(256) void k_gemm(const float* __restrict__ A,
                                              const float* __restrict__ W,
                                              const float* __restrict__ dinv,
                                              __half* __restrict__ u) {
    __shared__ float xt[32][64];
    __shared__ float ws[32][64];
    int t = threadIdx.x;
    int ti = t & 15;
    int tj = t >> 4;
    int node0 = blockIdx.x * 64;
    float acc[4][4] = {{0.f}};

    for (int kc = 0; kc < K; kc += 32) {
        if (kc) __syncthreads();
#pragma unroll
        for (int hh = 0; hh < 2; ++hh) {
            int f = t + 256 * hh;                       // 0..511
            int m = f >> 3, c = f & 7;
            int node = node0 + m;
            if (node >= N_NODES) node = N_NODES - 1;    // clamp (stores guarded)
            float4 v = *(const float4*)(A + (size_t)node * K + kc + 4 * c);
            int cs = (m + 4 * c) & 63;                  // swizzled column
            xt[4 * c + 0][cs] = v.x;
            xt[4 * c + 1][cs] = v.y;
            xt[4 * c + 2][cs] = v.z;
            xt[4 * c + 3][cs] = v.w;
            int kw = f >> 4, cw = f & 15;
            *(float4*)&ws[kw][4 * cw] =
                *(const float4*)(W + (size_t)(kc + kw) * D_H + 4 * cw);
        }
        __syncthreads();
#pragma unroll
        for (int k = 0; k < 32; ++k) {
            float4 xv = *(const float4*)&xt[k][(4 * tj + 4 * (k >> 2)) & 63];
            float4 wv = *(const float4*)&ws[k][4 * ti];
            float xa[4] = {xv.x, xv.y, xv.z, xv.w};
            float wa[4] = {wv.x, wv.y, wv.z, wv.w};
#pragma unroll
            for (int i = 0; i < 4; ++i)
#pragma unroll
                for (int j = 0; j < 4; ++j)
                    acc[i][j] = fmaf(xa[i], wa[j], acc[i][j]);
        }
    }
#pragma unroll
    for (int i = 0; i < 4; ++i) {
        int node = node0 + 4 * tj + i;
        if (node < N_NODES) {
            float dv = dinv[node];
            __half2* up = (__half2*)(u + (size_t)node * D_H + 4 * ti);
            up[0] = __floats2half2_rn(acc[i][0] * dv, acc[i][1] * dv);
            up[1] = __floats2half2_rn(acc[i][2] * dv, acc[i][3] * dv);
        }
    }
}

// fp16 A (layers 2/3, K = 64)
__global__ __launch_bounds__(256) void k_gemm_h(const __half* __restrict__ A,
                                                const float* __restrict__ W,
                                                const float* __restrict__ dinv,
                                                __half* __restrict__ u) {
    __shared__ float xt[32][64];
    __shared__ float ws[32][64];
    int t = threadIdx.x;
    int ti = t & 15;
    int tj = t >> 4;
    int node0 = blockIdx.x * 64;
    float acc[4][4] = {{0.f}};

    for (int kc = 0; kc < 64; kc += 32) {
        if (kc) __syncthreads();
#pragma unroll
        for (int hh = 0; hh < 2; ++hh) {
            int f = t + 256 * hh;                       // 0..511
            int m = f >> 3, c = f & 7;
            int node = node0 + m;
            if (node >= N_NODES) node = N_NODES - 1;    // clamp (stores guarded)
            uint2 v = *(const uint2*)(A + (size_t)node * D_H + kc + 4 * c);
            __half2 h0 = *reinterpret_cast<__half2*>(&v.x);
            __half2 h1 = *reinterpret_cast<__half2*>(&v.y);
            float2 f0 = __half22float2(h0);
            float2 f1 = __half22float2(h1);
            int cs = (m + 4 * c) & 63;                  // swizzled column
            xt[4 * c + 0][cs] = f0.x;
            xt[4 * c + 1][cs] = f0.y;
            xt[4 * c + 2][cs] = f1.x;
            xt[4 * c + 3][cs] = f1.y;
            int kw = f >> 4, cw = f & 15;
            *(float4*)&ws[kw][4 * cw] =
                *(const float4*)(W + (size_t)(kc + kw) * D_H + 4 * cw);
        }
        __syncthreads();
#pragma unroll
        for (int k = 0; k < 32; ++k) {
            float4 xv = *(const float4*)&xt[k][(4 * tj + 4 * (k >> 2)) & 63];
            float4 wv = *(const float4*)&ws[k][4 * ti];
            float xa[4] = {xv.x, xv.y, xv.z, xv.w};
            float wa[4] = {wv.x, wv.y, wv.z, wv.w};
#pragma unroll
            for (int i = 0; i < 4; ++i)
#pragma unroll
                for (int j = 0; j < 4; ++j)
                    acc[i][j] = fmaf(xa[i], wa[j], acc[i][j]);
        }
    }
#pragma unroll
    for (int i = 0; i < 4; ++i) {
        int node = node0 + 4 * tj + i;
        if (node < N_NODES) {
            float dv = dinv[node];
            __half2* up = (__half2*)(u + (size_t)node * D_H + 4 * ti);
            up[0] = __floats2half2_rn(acc[i][0] * dv, acc[i][1] * dv);
            up[1] = __floats2half2_rn(acc[i][2] * dv, acc[i][3] * dv);
        }
    }
}

// ------------- aggregation: 4 edges/wave, 8 B/lane, 8-deep pipeline -------
// Lists are padded to multiples of 32 -> remainder loop never runs; every
// edge flows through the full 8-deep pipeline.

__device__ __forceinline__ void acc4(float4& a, uint2 w) {
    __half2 h0 = *reinterpret_cast<__half2*>(&w.x);
    __half2 h1 = *reinterpret_cast<__half2*>(&w.y);
    float2 f0 = __half22float2(h0);
    float2 f1 = __half22float2(h1);
    a.x += f0.x; a.y += f0.y; a.z += f1.x; a.w += f1.y;
}

__device__ __forceinline__ float4 agg_gather4(const __half* __restrict__ u,
                                              const int* __restrict__ col,
                                              int beg, int end, int q, int fq) {
    float4 acc = make_float4(0.f, 0.f, 0.f, 0.f);
    int base = beg;
    for (; base + 31 < end; base += 32) {        // 32 edges/iter, 8 per sub-wave
        int e = base + q;
        int s0 = col[e],      s1 = col[e + 4],  s2 = col[e + 8],  s3 = col[e + 12];
        int s4 = col[e + 16], s5 = col[e + 20], s6 = col[e + 24], s7 = col[e + 28];
        uint2 w0 = *(const uint2*)(u + (size_t)s0 * D_H + fq * 4);
        uint2 w1 = *(const uint2*)(u + (size_t)s1 * D_H + fq * 4);
        uint2 w2 = *(const uint2*)(u + (size_t)s2 * D_H + fq * 4);
        uint2 w3 = *(const uint2*)(u + (size_t)s3 * D_H + fq * 4);
        uint2 w4 = *(const uint2*)(u + (size_t)s4 * D_H + fq * 4);
        uint2 w5 = *(const uint2*)(u + (size_t)s5 * D_H + fq * 4);
        uint2 w6 = *(const uint2*)(u + (size_t)s6 * D_H + fq * 4);
        uint2 w7 = *(const uint2*)(u + (size_t)s7 * D_H + fq * 4);
        acc4(acc, w0); acc4(acc, w1); acc4(acc, w2); acc4(acc, w3);
        acc4(acc, w4); acc4(acc, w5); acc4(acc, w6); acc4(acc, w7);
    }
    for (int e = base + q; e < end; e += 4) {    // safety; never runs (padded)
        uint2 w = *(const uint2*)(u + (size_t)col[e] * D_H + fq * 4);
        acc4(acc, w);
    }
    return acc;
}

// h[i] = half( relu( dinv[i] * (sum u[src] + u[i]) + b ) )
__global__ __launch_bounds__(256) void k_agg(const __half* __restrict__ u,
                                             const int* __restrict__ prowptr,
                                             const int* __restrict__ col,
                                             const float* __restrict__ dinv,
                                             const float* __restrict__ b,
                                             __half* __restrict__ h) {
    int t = threadIdx.x;
    int lane = t & 63, q = lane >> 4, fq = lane & 15;
    int node = (blockIdx.x * blockDim.x + t) >> 6;
    if (node >= N_NODES) return;
    float4 acc = agg_gather4(u, col, prowptr[node], prowptr[node + 1], q, fq);
    if (q == 0) {                                // self loop, counted once
        uint2 w = *(const uint2*)(u + (size_t)node * D_H + fq * 4);
        acc4(acc, w);
    }
    acc.x += __shfl_xor(acc.x, 16, 64); acc.y += __shfl_xor(acc.y, 16, 64);
    acc.z += __shfl_xor(acc.z, 16, 64); acc.w += __shfl_xor(acc.w, 16, 64);
    acc.x += __shfl_xor(acc.x, 32, 64); acc.y += __shfl_xor(acc.y, 32, 64);
    acc.z += __shfl_xor(acc.z, 32, 64); acc.w += __shfl_xor(acc.w, 32, 64);
    if (q == 0) {
        float dv = dinv[node];
        float4 bb = *(const float4*)(b + 4 * fq);
        uint2 o;
        __half2 o0 = __floats2half2_rn(fmaxf(acc.x * dv + bb.x, 0.f),
                                       fmaxf(acc.y * dv + bb.y, 0.f));
        __half2 o1 = __floats2half2_rn(fmaxf(acc.z * dv + bb.z, 0.f),
                                       fmaxf(acc.w * dv + bb.w, 0.f));
        o.x = *reinterpret_cast<unsigned*>(&o0);
        o.y = *reinterpret_cast<unsigned*>(&o1);
        *(uint2*)(h + (size_t)node * D_H + 4 * fq) = o;
    }
}

// layer 3 + head: val[i] = dot(agg_row*dinv + b, Wl)
__global__ __launch_bounds__(256) void k_agg_dot(const __half* __restrict__ uin,
                                                 const int* __restrict__ prowptr,
                                                 const int* __restrict__ col,
                                                 const float* __restrict__ dinv,
                                                 const float* __restrict__ b,
                                                 const float* __restrict__ Wl,
                                                 float* __restrict__ val) {
    int t = threadIdx.x;
    int lane = t & 63, q = lane >> 4, fq = lane & 15;
    int node = (blockIdx.x * blockDim.x + t) >> 6;
    if (node >= N_NODES) return;
    float4 acc = agg_gather4(uin, col, prowptr[node], prowptr[node + 1], q, fq);
    if (q == 0) {                                // self loop, counted once
        uint2 w = *(const uint2*)(uin + (size_t)node * D_H + fq * 4);
        acc4(acc, w);
    }
    float4 wl = *(const float4*)(Wl + 4 * fq);
    float dv = dinv[node];
    float v = dv * (acc.x * wl.x + acc.y * wl.y + acc.z * wl.z + acc.w * wl.w);
    if (q == 0) {                                // bias term, counted once
        float4 bb = *(const float4*)(b + 4 * fq);
        v += bb.x * wl.x + bb.y * wl.y + bb.z * wl.z + bb.w * wl.w;
    }
#pragma unroll
    for (int m = 32; m > 0; m >>= 1) v += __shfl_xor(v, m, 64);
    if (lane == 0) val[node] = v;
}

// one block per graph: batch is sorted, binary-search the segment, reduce.
__global__ __launch_bounds__(256) void k_gpool(const float* __restrict__ val,
                                               const int* __restrict__ batch,
                                               const float* __restrict__ bl,
                                               float* __restrict__ out) {
    int g = blockIdx.x;
    int l = 0, r = N_NODES;
    while (l < r) { int m = (l + r) >> 1; if (batch[m] < g) l = m + 1; else r = m; }
    int lo = l;
    r = N_NODES;
    while (l < r) { int m = (l + r) >> 1; if (batch[m] < g + 1) l = m + 1; else r = m; }
    int hi = l;
    float s = 0.0f;
    for (int i = lo + threadIdx.x; i < hi; i += 256) s += val[i];
#pragma unroll
    for (int m = 32; m > 0; m >>= 1) s += __shfl_xor(s, m, 64);
    __shared__ float red[4];
    int wid = threadIdx.x >> 6, lane = threadIdx.x & 63;
    if (lane == 0) red[wid] = s;
    __syncthreads();
    if (threadIdx.x == 0) {
        float t = red[0] + red[1] + red[2] + red[3];
        out[g] = t / fmaxf((float)(hi - lo), 1.0f) + bl[0];
    }
}

// ---------------- launch ----------------

extern "C" void kernel_launch(void* const* d_in, const int* in_sizes, int n_in,
                              void* d_out, int out_size, void* d_ws, size_t ws_size,
                              hipStream_t stream) {
    const float* x   = (const float*)d_in[0];
    const int*   ei  = (const int*)d_in[1];
    const int*   bat = (const int*)d_in[2];
    const float* W1  = (const float*)d_in[3];
    const float* b1  = (const float*)d_in[4];
    const float* W2  = (const float*)d_in[5];
    const float* b2  = (const float*)d_in[6];
    const float* W3  = (const float*)d_in[7];
    const float* b3  = (const float*)d_in[8];
    const float* Wl  = (const float*)d_in[9];
    const float* bl  = (const float*)d_in[10];
    float* out = (float*)d_out;

    char* p = (char*)d_ws;
    auto alloc = [&](size_t bytes) -> void* {
        void* r = (void*)p;
        p += (bytes + 255) & ~(size_t)255;
        return r;
    };
    int*    ghist    = (int*)alloc((size_t)NBIN * 4);
    int*    binbase  = (int*)alloc((size_t)(NBIN + 1) * 4);
    int*    gcur     = (int*)alloc((size_t)NBIN * 4);
    int*    pbin     = (int*)alloc((size_t)NBIN * 4);
    int*    pbinbase = (int*)alloc((size_t)(NBIN + 1) * 4);
    int*    lofs     = (int*)alloc((size_t)NBIN * 256 * 4);
    int*    prowptr  = (int*)alloc((size_t)(N_NODES + 1) * 4);
    float*  dinv     = (float*)alloc((size_t)N_NODES * 4);
    int*    colb     = (int*)alloc((size_t)COLB_CAP * 4);
    int*    ebuf     = (int*)alloc((size_t)N_EDGES * 4);
    __half* u        = (__half*)alloc((size_t)(N_NODES + 1) * D_H * 2);
    __half* h        = (__half*)alloc((size_t)N_NODES * D_H * 2);
    float*  val      = (float*)alloc((size_t)N_NODES * 4);

    hipMemsetAsync(ghist, 0, (size_t)NBIN * 4, stream);

    const int* srcp = ei;
    const int* dstp = ei + N_EDGES;

    int wbl = (N_NODES * 64 + 255) / 256;           // one wave per node
    int gbl = (N_NODES + 63) / 64;

    // CSR build (padded lists, sentinel -> zero row)
    k_hist<<<HIST_BLOCKS, 256, 0, stream>>>(dstp, ghist);
    k_scanbins<<<1, 512, 0, stream>>>(ghist, binbase, gcur);
    k_part<<<PART_BLOCKS, 256, 0, stream>>>(srcp, dstp, gcur, ebuf);
    k_binpad<<<NBIN, 256, 0, stream>>>(binbase, ebuf, pbin, lofs, dinv);
    k_scanp<<<1, 512, 0, stream>>>(pbin, pbinbase, prowptr, u);
    k_sortbin<<<NBIN, 256, 0, stream>>>(binbase, pbinbase, lofs, ebuf, colb, prowptr);

    // layer 1: 320 -> 64
    k_gemm<D_IN><<<gbl, 256, 0, stream>>>(x, W1, dinv, u);
    k_agg<<<wbl, 256, 0, stream>>>(u, prowptr, colb, dinv, b1, h);
    // layer 2: 64 -> 64 (fp16 h input)
    k_gemm_h<<<gbl, 256, 0, stream>>>(h, W2, dinv, u);
    k_agg<<<wbl, 256, 0, stream>>>(u, prowptr, colb, dinv, b2, h);
    // layer 3: 64 -> 64, fused with linear head dot
    k_gemm_h<<<gbl, 256, 0, stream>>>(h, W3, dinv, u);
    k_agg_dot<<<wbl, 256, 0, stream>>>(u, prowptr, colb, dinv, b3, Wl, val);

    // pooling
    k_gpool<<<N_GRAPHS, 256, 0, stream>>>(val, bat, bl, out);
}

// Round 16
// 335.244 us; speedup vs baseline: 1.1616x; 1.1616x over previous
//
#include <hip/hip_runtime.h>
#include <hip/hip_bf16.h>
#include <hip/hip_fp16.h>

#define N_NODES 100000
#define N_EDGES 3200000
#define N_GRAPHS 256
#define D_IN 320
#define D_H 64

#define NBIN 391                    // ceil(N_NODES / 256) bins of 256 dst nodes
#define BIN_CAP 14336               // padded bin ~12154, sigma~172 -> +12 sigma
#define HIST_BLOCKS 256
#define HIST_CHUNK ((N_EDGES + HIST_BLOCKS - 1) / HIST_BLOCKS)
#define PART_BLOCKS 200
#define PART_CHUNK ((N_EDGES + PART_BLOCKS - 1) / PART_BLOCKS)   // 16000
#define COLB_CAP 5500000            // padded edges ~4.75M

// ---------------- CSR build (block-private chunk partition) ----------------

__global__ __launch_bounds__(256) void k_hist(const int* __restrict__ dst,
                                              int* __restrict__ ghist) {
    __shared__ int lh[NBIN];
    for (int i = threadIdx.x; i < NBIN; i += 256) lh[i] = 0;
    __syncthreads();
    int beg = blockIdx.x * HIST_CHUNK;
    int end = min(beg + HIST_CHUNK, N_EDGES);
    for (int e = beg + threadIdx.x; e < end; e += 256)
        atomicAdd(&lh[dst[e] >> 8], 1);
    __syncthreads();
    for (int i = threadIdx.x; i < NBIN; i += 256)
        if (lh[i]) atomicAdd(&ghist[i], lh[i]);
}

// scan real bin counts -> compact binbase (for ebuf) + gcur
__global__ __launch_bounds__(512) void k_scanbins(const int* __restrict__ ghist,
                                                  int* __restrict__ binbase,
                                                  int* __restrict__ gcur) {
    __shared__ int sa[512], sb[512];
    int t = threadIdx.x;
    int v = (t < NBIN) ? ghist[t] : 0;
    sa[t] = v;
    __syncthreads();
    int* in = sa; int* out = sb;
    for (int off = 1; off < 512; off <<= 1) {
        out[t] = in[t] + (t >= off ? in[t - off] : 0);
        __syncthreads();
        int* tmp = in; in = out; out = tmp;
    }
    int excl = in[t] - v;
    if (t < NBIN) { binbase[t] = excl; gcur[t] = excl; }
    if (t == 511) binbase[NBIN] = in[511];
}

// partition edges into 391 bins; block-private contiguous chunks per bin.
__global__ __launch_bounds__(256) void k_part(const int* __restrict__ src,
                                              const int* __restrict__ dst,
                                              int* __restrict__ gcur,
                                              int* __restrict__ ebuf) {
    __shared__ int lh[NBIN], gb[NBIN], cur[NBIN];
    for (int i = threadIdx.x; i < NBIN; i += 256) { lh[i] = 0; cur[i] = 0; }
    __syncthreads();
    int beg = blockIdx.x * PART_CHUNK;
    int end = min(beg + PART_CHUNK, N_EDGES);
    for (int e = beg + threadIdx.x; e < end; e += 256)
        atomicAdd(&lh[dst[e] >> 8], 1);
    __syncthreads();
    for (int i = threadIdx.x; i < NBIN; i += 256)
        gb[i] = lh[i] ? atomicAdd(&gcur[i], lh[i]) : 0;
    __syncthreads();
    for (int e = beg + threadIdx.x; e < end; e += 256) {
        int d = dst[e], s = src[e];
        int bin = d >> 8;
        int r = atomicAdd(&cur[bin], 1);
        ebuf[gb[bin] + r] = ((d & 255) << 17) | s;   // dst-low-8 | src(17b)
    }
}

// per bin: per-node degree -> padded degree (mult of 32), packed local
// offset+degree (lofs = excl | deg<<14), dinv, padded bin total.
__global__ __launch_bounds__(256) void k_binpad(const int* __restrict__ binbase,
                                                const int* __restrict__ ebuf,
                                                int* __restrict__ pbin,
                                                int* __restrict__ lofs,
                                                float* __restrict__ dinv) {
    __shared__ int hc[256], sa[256], sb[256];
    int b = blockIdx.x, t = threadIdx.x;
    int e0 = binbase[b], e1 = binbase[b + 1];
    hc[t] = 0;
    __syncthreads();
    for (int i = e0 + t; i < e1; i += 256)
        atomicAdd(&hc[ebuf[i] >> 17], 1);
    __syncthreads();
    int deg = hc[t];
    int pdeg = (deg + 31) & ~31;
    sa[t] = pdeg;
    __syncthreads();
    int* in = sa; int* out = sb;
    for (int o = 1; o < 256; o <<= 1) {
        out[t] = in[t] + (t >= o ? in[t - o] : 0);
        __syncthreads();
        int* tm = in; in = out; out = tm;
    }
    int excl = in[t] - pdeg;
    lofs[(b << 8) + t] = excl | (deg << 14);         // excl < 2^14
    int node = (b << 8) + t;
    if (node < N_NODES) dinv[node] = rsqrtf((float)(deg + 1));  // +1 self loop
    if (t == 255) pbin[b] = in[255];
}

// scan padded bin totals -> pbinbase; prowptr[N]; zero u pad row + z pad.
__global__ __launch_bounds__(512) void k_scanp(const int* __restrict__ pbin,
                                               int* __restrict__ pbinbase,
                                               int* __restrict__ prowptr,
                                               __half* __restrict__ u,
                                               float* __restrict__ z) {
    __shared__ int sa[512], sb[512];
    int t = threadIdx.x;
    int v = (t < NBIN) ? pbin[t] : 0;
    sa[t] = v;
    __syncthreads();
    int* in = sa; int* out = sb;
    for (int off = 1; off < 512; off <<= 1) {
        out[t] = in[t] + (t >= off ? in[t - off] : 0);
        __syncthreads();
        int* tmp = in; in = out; out = tmp;
    }
    int excl = in[t] - v;
    if (t < NBIN) pbinbase[t] = excl;
    if (t == 511) { pbinbase[NBIN] = in[511]; prowptr[N_NODES] = in[511]; }
    if (t < 32) ((unsigned*)(u + (size_t)N_NODES * D_H))[t] = 0u;  // zero row
    if (t == 32) z[N_NODES] = 0.f;                                 // zero pad
}

// per bin: place edges at padded local offsets (deg from packed lofs -> no
// histogram pass), fill pads with sentinel, write col coalesced; emit prowptr.
__global__ __launch_bounds__(256) void k_sortbin(const int* __restrict__ binbase,
                                                 const int* __restrict__ pbinbase,
                                                 const int* __restrict__ lofs,
                                                 const int* __restrict__ ebuf,
                                                 int* __restrict__ col,
                                                 int* __restrict__ prowptr) {
    __shared__ int sc[256];
    __shared__ int scol[BIN_CAP];
    int b = blockIdx.x, t = threadIdx.x;
    int d0 = b << 8;
    int e0 = binbase[b], e1 = binbase[b + 1];
    int pb0 = pbinbase[b], pb1 = pbinbase[b + 1];
    int lv = lofs[d0 + t];
    int lb = lv & 0x3FFF;
    int deg = lv >> 14;
    int pdeg = (deg + 31) & ~31;
    sc[t] = lb;
    int node = d0 + t;
    if (node < N_NODES) prowptr[node] = pb0 + lb;
    __syncthreads();
    for (int i = e0 + t; i < e1; i += 256) {
        int pk = ebuf[i];
        int p = atomicAdd(&sc[pk >> 17], 1);
        if (p < BIN_CAP) scol[p] = pk & 0x1FFFF;
    }
    __syncthreads();
    for (int j = lb + deg; j < lb + pdeg; ++j)
        if (j < BIN_CAP) scol[j] = N_NODES;          // sentinel -> zero row
    __syncthreads();
    int n = pb1 - pb0;
    for (int i = t; i < n; i += 256) col[pb0 + i] = scol[i];
}

// ---------------- head-fold precompute: w3l = W3 @ Wl, bwl = b3 . Wl ------
__global__ void k_w3l(const float* __restrict__ W3, const float* __restrict__ Wl,
                      const float* __restrict__ b3, float* __restrict__ w3lb) {
    int k = threadIdx.x;                 // 64 threads
    float s = 0.f;
#pragma unroll
    for (int j = 0; j < 64; ++j) s = fmaf(W3[k * 64 + j], Wl[j], s);
    w3lb[k] = s;
    float bs = b3[k] * Wl[k];
#pragma unroll
    for (int m = 32; m > 0; m >>= 1) bs += __shfl_xor(bs, m, 64);
    if (k == 0) w3lb[64] = bs;
}

// ---------------- tiled GEMM transforms ----------------
// u[node][f] = half( (A[node,:] @ W)[f] * dinv[node] )

// fp32 A (layer 1, K = 320)
template<int K>
__global__ __launch_bounds__(256) void k_gemm(const float* __restrict__ A,
                                              const float* __restrict__ W,
                                              const float* __restrict__ dinv,
                                              __half* __restrict__ u) {
    __shared__ float xt[32][64];
    __shared__ float ws[32][64];
    int t = threadIdx.x;
    int ti = t & 15;
    int tj = t >> 4;
    int node0 = blockIdx.x * 64;
    float acc[4][4] = {{0.f}};

    for (int kc = 0; kc < K; kc += 32) {
        if (kc) __syncthreads();
#pragma unroll
        for (int hh = 0; hh < 2; ++hh) {
            int f = t + 256 * hh;                       // 0..511
            int m = f >> 3, c = f & 7;
            int node = node0 + m;
            if (node >= N_NODES) node = N_NODES - 1;    // clamp (stores guarded)
            float4 v = *(const float4*)(A + (size_t)node * K + kc + 4 * c);
            int cs = (m + 4 * c) & 63;                  // swizzled column
            xt[4 * c + 0][cs] = v.x;
            xt[4 * c + 1][cs] = v.y;
            xt[4 * c + 2][cs] = v.z;
            xt[4 * c + 3][cs] = v.w;
            int kw = f >> 4, cw = f & 15;
            *(float4*)&ws[kw][4 * cw] =
                *(const float4*)(W + (size_t)(kc + kw) * D_H + 4 * cw);
        }
        __syncthreads();
#pragma unroll
        for (int k = 0; k < 32; ++k) {
            float4 xv = *(const float4*)&xt[k][(4 * tj + 4 * (k >> 2)) & 63];
            float4 wv = *(const float4*)&ws[k][4 * ti];
            float xa[4] = {xv.x, xv.y, xv.z, xv.w};
            float wa[4] = {wv.x, wv.y, wv.z, wv.w};
#pragma unroll
            for (int i = 0; i < 4; ++i)
#pragma unroll
                for (int j = 0; j < 4; ++j)
                    acc[i][j] = fmaf(xa[i], wa[j], acc[i][j]);
        }
    }
#pragma unroll
    for (int i = 0; i < 4; ++i) {
        int node = node0 + 4 * tj + i;
        if (node < N_NODES) {
            float dv = dinv[node];
            __half2* up = (__half2*)(u + (size_t)node * D_H + 4 * ti);
            up[0] = __floats2half2_rn(acc[i][0] * dv, acc[i][1] * dv);
            up[1] = __floats2half2_rn(acc[i][2] * dv, acc[i][3] * dv);
        }
    }
}

// fp16 A (layer 2, K = 64)
__global__ __launch_bounds__(256) void k_gemm_h(const __half* __restrict__ A,
                                                const float* __restrict__ W,
                                                const float* __restrict__ dinv,
                                                __half* __restrict__ u) {
    __shared__ float xt[32][64];
    __shared__ float ws[32][64];
    int t = threadIdx.x;
    int ti = t & 15;
    int tj = t >> 4;
    int node0 = blockIdx.x * 64;
    float acc[4][4] = {{0.f}};

    for (int kc = 0; kc < 64; kc += 32) {
        if (kc) __syncthreads();
#pragma unroll
        for (int hh = 0; hh < 2; ++hh) {
            int f = t + 256 * hh;                       // 0..511
            int m = f >> 3, c = f & 7;
            int node = node0 + m;
            if (node >= N_NODES) node = N_NODES - 1;    // clamp (stores guarded)
            uint2 v = *(const uint2*)(A + (size_t)node * D_H + kc + 4 * c);
            __half2 h0 = *reinterpret_cast<__half2*>(&v.x);
            __half2 h1 = *reinterpret_cast<__half2*>(&v.y);
            float2 f0 = __half22float2(h0);
            float2 f1 = __half22float2(h1);
            int cs = (m + 4 * c) & 63;                  // swizzled column
            xt[4 * c + 0][cs] = f0.x;
            xt[4 * c + 1][cs] = f0.y;
            xt[4 * c + 2][cs] = f1.x;
            xt[4 * c + 3][cs] = f1.y;
            int kw = f >> 4, cw = f & 15;
            *(float4*)&ws[kw][4 * cw] =
                *(const float4*)(W + (size_t)(kc + kw) * D_H + 4 * cw);
        }
        __syncthreads();
#pragma unroll
        for (int k = 0; k < 32; ++k) {
            float4 xv = *(const float4*)&xt[k][(4 * tj + 4 * (k >> 2)) & 63];
            float4 wv = *(const float4*)&ws[k][4 * ti];
            float xa[4] = {xv.x, xv.y, xv.z, xv.w};
            float wa[4] = {wv.x, wv.y, wv.z, wv.w};
#pragma unroll
            for (int i = 0; i < 4; ++i)
#pragma unroll
                for (int j = 0; j < 4; ++j)
                    acc[i][j] = fmaf(xa[i], wa[j], acc[i][j]);
        }
    }
#pragma unroll
    for (int i = 0; i < 4; ++i) {
        int node = node0 + 4 * tj + i;
        if (node < N_NODES) {
            float dv = dinv[node];
            __half2* up = (__half2*)(u + (size_t)node * D_H + 4 * ti);
            up[0] = __floats2half2_rn(acc[i][0] * dv, acc[i][1] * dv);
            up[1] = __floats2half2_rn(acc[i][2] * dv, acc[i][3] * dv);
        }
    }
}

// ------------- aggregation: 4 edges/wave, 8 B/lane, 8-deep pipeline -------

__device__ __forceinline__ void acc4(float4& a, uint2 w) {
    __half2 h0 = *reinterpret_cast<__half2*>(&w.x);
    __half2 h1 = *reinterpret_cast<__half2*>(&w.y);
    float2 f0 = __half22float2(h0);
    float2 f1 = __half22float2(h1);
    a.x += f0.x; a.y += f0.y; a.z += f1.x; a.w += f1.y;
}

__device__ __forceinline__ float4 agg_gather4(const __half* __restrict__ u,
                                              const int* __restrict__ col,
                                              int beg, int end, int q, int fq) {
    float4 acc = make_float4(0.f, 0.f, 0.f, 0.f);
    int base = beg;
    for (; base + 31 < end; base += 32) {        // 32 edges/iter, 8 per sub-wave
        int e = base + q;
        int s0 = col[e],      s1 = col[e + 4],  s2 = col[e + 8],  s3 = col[e + 12];
        int s4 = col[e + 16], s5 = col[e + 20], s6 = col[e + 24], s7 = col[e + 28];
        uint2 w0 = *(const uint2*)(u + (size_t)s0 * D_H + fq * 4);
        uint2 w1 = *(const uint2*)(u + (size_t)s1 * D_H + fq * 4);
        uint2 w2 = *(const uint2*)(u + (size_t)s2 * D_H + fq * 4);
        uint2 w3 = *(const uint2*)(u + (size_t)s3 * D_H + fq * 4);
        uint2 w4 = *(const uint2*)(u + (size_t)s4 * D_H + fq * 4);
        uint2 w5 = *(const uint2*)(u + (size_t)s5 * D_H + fq * 4);
        uint2 w6 = *(const uint2*)(u + (size_t)s6 * D_H + fq * 4);
        uint2 w7 = *(const uint2*)(u + (size_t)s7 * D_H + fq * 4);
        acc4(acc, w0); acc4(acc, w1); acc4(acc, w2); acc4(acc, w3);
        acc4(acc, w4); acc4(acc, w5); acc4(acc, w6); acc4(acc, w7);
    }
    for (int e = base + q; e < end; e += 4) {    // safety; never runs (padded)
        uint2 w = *(const uint2*)(u + (size_t)col[e] * D_H + fq * 4);
        acc4(acc, w);
    }
    return acc;
}

// h[i] = half( relu( dinv[i] * (sum u[src] + u[i]) + b ) )
__global__ __launch_bounds__(256) void k_agg(const __half* __restrict__ u,
                                             const int* __restrict__ prowptr,
                                             const int* __restrict__ col,
                                             const float* __restrict__ dinv,
                                             const float* __restrict__ b,
                                             __half* __restrict__ h) {
    int t = threadIdx.x;
    int lane = t & 63, q = lane >> 4, fq = lane & 15;
    int node = (blockIdx.x * blockDim.x + t) >> 6;
    if (node >= N_NODES) return;
    float4 acc = agg_gather4(u, col, prowptr[node], prowptr[node + 1], q, fq);
    if (q == 0) {                                // self loop, counted once
        uint2 w = *(const uint2*)(u + (size_t)node * D_H + fq * 4);
        acc4(acc, w);
    }
    acc.x += __shfl_xor(acc.x, 16, 64); acc.y += __shfl_xor(acc.y, 16, 64);
    acc.z += __shfl_xor(acc.z, 16, 64); acc.w += __shfl_xor(acc.w, 16, 64);
    acc.x += __shfl_xor(acc.x, 32, 64); acc.y += __shfl_xor(acc.y, 32, 64);
    acc.z += __shfl_xor(acc.z, 32, 64); acc.w += __shfl_xor(acc.w, 32, 64);
    if (q == 0) {
        float dv = dinv[node];
        float4 bb = *(const float4*)(b + 4 * fq);
        uint2 o;
        __half2 o0 = __floats2half2_rn(fmaxf(acc.x * dv + bb.x, 0.f),
                                       fmaxf(acc.y * dv + bb.y, 0.f));
        __half2 o1 = __floats2half2_rn(fmaxf(acc.z * dv + bb.z, 0.f),
                                       fmaxf(acc.w * dv + bb.w, 0.f));
        o.x = *reinterpret_cast<unsigned*>(&o0);
        o.y = *reinterpret_cast<unsigned*>(&o1);
        *(uint2*)(h + (size_t)node * D_H + 4 * fq) = o;
    }
}

// layer-2 agg with layer-3 head fold:
// z[i] = dinv[i] * dot( relu(dinv[i]*(sum u[src]+u[i]) + b2), w3l )
__global__ __launch_bounds__(256) void k_agg_z(const __half* __restrict__ u,
                                               const int* __restrict__ prowptr,
                                               const int* __restrict__ col,
                                               const float* __restrict__ dinv,
                                               const float* __restrict__ b,
                                               const float* __restrict__ w3lb,
                                               float* __restrict__ z) {
    int t = threadIdx.x;
    int lane = t & 63, q = lane >> 4, fq = lane & 15;
    int node = (blockIdx.x * blockDim.x + t) >> 6;
    if (node >= N_NODES) return;
    float4 acc = agg_gather4(u, col, prowptr[node], prowptr[node + 1], q, fq);
    if (q == 0) {                                // self loop, counted once
        uint2 w = *(const uint2*)(u + (size_t)node * D_H + fq * 4);
        acc4(acc, w);
    }
    acc.x += __shfl_xor(acc.x, 16, 64); acc.y += __shfl_xor(acc.y, 16, 64);
    acc.z += __shfl_xor(acc.z, 16, 64); acc.w += __shfl_xor(acc.w, 16, 64);
    acc.x += __shfl_xor(acc.x, 32, 64); acc.y += __shfl_xor(acc.y, 32, 64);
    acc.z += __shfl_xor(acc.z, 32, 64); acc.w += __shfl_xor(acc.w, 32, 64);
    // all lanes now hold the full sums for features 4fq..4fq+3
    float dv = dinv[node];
    float4 bb = *(const float4*)(b + 4 * fq);
    float4 wv = *(const float4*)(w3lb + 4 * fq);
    float h0 = fmaxf(acc.x * dv + bb.x, 0.f);
    float h1 = fmaxf(acc.y * dv + bb.y, 0.f);
    float h2v = fmaxf(acc.z * dv + bb.z, 0.f);
    float h3v = fmaxf(acc.w * dv + bb.w, 0.f);
    float s = h0 * wv.x + h1 * wv.y + h2v * wv.z + h3v * wv.w;
#pragma unroll
    for (int m = 8; m > 0; m >>= 1) s += __shfl_xor(s, m, 64);
    if (lane == 0) z[node] = s * dv;
}

// layer-3 aggregation on scalars: val[dst] = dinv*(sum z[src] + z[dst]) + bwl
__global__ __launch_bounds__(256) void k_aggz(const float* __restrict__ z,
                                              const int* __restrict__ prowptr,
                                              const int* __restrict__ col,
                                              const float* __restrict__ dinv,
                                              const float* __restrict__ w3lb,
                                              float* __restrict__ val) {
    int t = threadIdx.x;
    int lane = t & 63;
    int node = (blockIdx.x * blockDim.x + t) >> 6;
    if (node >= N_NODES) return;
    int beg = prowptr[node], end = prowptr[node + 1];
    float a = 0.f;
    for (int e = beg + lane; e < end; e += 64) a += z[col[e]];
#pragma unroll
    for (int m = 32; m > 0; m >>= 1) a += __shfl_xor(a, m, 64);
    if (lane == 0) val[node] = dinv[node] * (a + z[node]) + w3lb[64];
}

// one block per graph: batch is sorted, binary-search the segment, reduce.
__global__ __launch_bounds__(256) void k_gpool(const float* __restrict__ val,
                                               const int* __restrict__ batch,
                                               const float* __restrict__ bl,
                                               float* __restrict__ out) {
    int g = blockIdx.x;
    int l = 0, r = N_NODES;
    while (l < r) { int m = (l + r) >> 1; if (batch[m] < g) l = m + 1; else r = m; }
    int lo = l;
    r = N_NODES;
    while (l < r) { int m = (l + r) >> 1; if (batch[m] < g + 1) l = m + 1; else r = m; }
    int hi = l;
    float s = 0.0f;
    for (int i = lo + threadIdx.x; i < hi; i += 256) s += val[i];
#pragma unroll
    for (int m = 32; m > 0; m >>= 1) s += __shfl_xor(s, m, 64);
    __shared__ float red[4];
    int wid = threadIdx.x >> 6, lane = threadIdx.x & 63;
    if (lane == 0) red[wid] = s;
    __syncthreads();
    if (threadIdx.x == 0) {
        float t = red[0] + red[1] + red[2] + red[3];
        out[g] = t / fmaxf((float)(hi - lo), 1.0f) + bl[0];
    }
}

// ---------------- launch ----------------

extern "C" void kernel_launch(void* const* d_in, const int* in_sizes, int n_in,
                              void* d_out, int out_size, void* d_ws, size_t ws_size,
                              hipStream_t stream) {
    const float* x   = (const float*)d_in[0];
    const int*   ei  = (const int*)d_in[1];
    const int*   bat = (const int*)d_in[2];
    const float* W1  = (const float*)d_in[3];
    const float* b1  = (const float*)d_in[4];
    const float* W2  = (const float*)d_in[5];
    const float* b2  = (const float*)d_in[6];
    const float* W3  = (const float*)d_in[7];
    const float* b3  = (const float*)d_in[8];
    const float* Wl  = (const float*)d_in[9];
    const float* bl  = (const float*)d_in[10];
    float* out = (float*)d_out;

    char* p = (char*)d_ws;
    auto alloc = [&](size_t bytes) -> void* {
        void* r = (void*)p;
        p += (bytes + 255) & ~(size_t)255;
        return r;
    };
    int*    ghist    = (int*)alloc((size_t)NBIN * 4);
    int*    binbase  = (int*)alloc((size_t)(NBIN + 1) * 4);
    int*    gcur     = (int*)alloc((size_t)NBIN * 4);
    int*    pbin     = (int*)alloc((size_t)NBIN * 4);
    int*    pbinbase = (int*)alloc((size_t)(NBIN + 1) * 4);
    int*    lofs     = (int*)alloc((size_t)NBIN * 256 * 4);
    int*    prowptr  = (int*)alloc((size_t)(N_NODES + 1) * 4);
    float*  dinv     = (float*)alloc((size_t)N_NODES * 4);
    int*    colb     = (int*)alloc((size_t)COLB_CAP * 4);
    int*    ebuf     = (int*)alloc((size_t)N_EDGES * 4);
    __half* u        = (__half*)alloc((size_t)(N_NODES + 1) * D_H * 2);
    __half* h        = (__half*)alloc((size_t)N_NODES * D_H * 2);
    float*  z        = (float*)alloc((size_t)(N_NODES + 1) * 4);
    float*  w3lb     = (float*)alloc((size_t)256);
    float*  val      = (float*)alloc((size_t)N_NODES * 4);

    hipMemsetAsync(ghist, 0, (size_t)NBIN * 4, stream);

    const int* srcp = ei;
    const int* dstp = ei + N_EDGES;

    int wbl = (N_NODES * 64 + 255) / 256;           // one wave per node
    int gbl = (N_NODES + 63) / 64;

    // CSR build (padded lists, sentinel -> zero row)
    k_hist<<<HIST_BLOCKS, 256, 0, stream>>>(dstp, ghist);
    k_scanbins<<<1, 512, 0, stream>>>(ghist, binbase, gcur);
    k_part<<<PART_BLOCKS, 256, 0, stream>>>(srcp, dstp, gcur, ebuf);
    k_binpad<<<NBIN, 256, 0, stream>>>(binbase, ebuf, pbin, lofs, dinv);
    k_scanp<<<1, 512, 0, stream>>>(pbin, pbinbase, prowptr, u, z);
    k_sortbin<<<NBIN, 256, 0, stream>>>(binbase, pbinbase, lofs, ebuf, colb, prowptr);
    k_w3l<<<1, 64, 0, stream>>>(W3, Wl, b3, w3lb);

    // layer 1: 320 -> 64
    k_gemm<D_IN><<<gbl, 256, 0, stream>>>(x, W1, dinv, u);
    k_agg<<<wbl, 256, 0, stream>>>(u, prowptr, colb, dinv, b1, h);
    // layer 2: 64 -> 64, epilogue folds layer-3 head: z = dinv * (h2 . w3l)
    k_gemm_h<<<gbl, 256, 0, stream>>>(h, W2, dinv, u);
    k_agg_z<<<wbl, 256, 0, stream>>>(u, prowptr, colb, dinv, b2, w3lb, z);
    // layer 3 collapsed to scalar aggregation
    k_aggz<<<wbl, 256, 0, stream>>>(z, prowptr, colb, dinv, w3lb, val);

    // pooling
    k_gpool<<<N_GRAPHS, 256, 0, stream>>>(val, bat, bl, out);
}